// Round 17
// baseline (197.657 us; speedup 1.0000x reference)
//
#include <hip/hip_runtime.h>
#include <hip/hip_bf16.h>
#include <stdint.h>

// Problem constants: B=4, S=2048, D=1024, H=16, HD=64
#define B_  4
#define S_  2048
#define D_  1024
#define H_  16
#define HD_ 64

typedef __attribute__((ext_vector_type(8))) short          s16x8;   // MFMA A/B frag (8 bf16)
typedef __attribute__((ext_vector_type(4))) float          f32x4;   // MFMA C/D frag
typedef __attribute__((ext_vector_type(8))) unsigned short u16x8;   // 16B bf16 chunk

__device__ __forceinline__ unsigned short f2bf(float f) {
  union { float f; unsigned int u; } v; v.f = f;
  unsigned int u = v.u;
  u += 0x7fffu + ((u >> 16) & 1u);       // RNE
  return (unsigned short)(u >> 16);
}

// bare v_exp_f32 (2^x); exp2f without -ffast-math is OCML guarded code.
#if __has_builtin(__builtin_amdgcn_exp2f)
#define EXP2(x) __builtin_amdgcn_exp2f(x)
#else
#define EXP2(x) exp2f(x)
#endif

// async global->LDS, 16B per lane; LDS dest = wave-uniform base + lane*16
#define GLDS16(g, l)                                                           \
  __builtin_amdgcn_global_load_lds(                                            \
      (const __attribute__((address_space(1))) void*)(g),                      \
      (__attribute__((address_space(3))) void*)(l), 16, 0, 0)

// ---------------------------------------------------------------- converts
__global__ void k_cvt(const float* __restrict__ src, unsigned short* __restrict__ dst, int n4) {
  int i = blockIdx.x * blockDim.x + threadIdx.x;
  int stride = gridDim.x * blockDim.x;
  for (int j = i; j < n4; j += stride) {
    float4 v = reinterpret_cast<const float4*>(src)[j];
    ushort4 o;
    o.x = f2bf(v.x); o.y = f2bf(v.y); o.z = f2bf(v.z); o.w = f2bf(v.w);
    reinterpret_cast<ushort4*>(dst)[j] = o;
  }
}

// fp32 [R][C] -> bf16 [C][R]   (weights -> B^T layout for gemm-BT)
__global__ void k_tpose_cvt(const float* __restrict__ src, unsigned short* __restrict__ dst,
                            int R, int C) {
  __shared__ unsigned short tile[64][72];
  int c0 = blockIdx.x * 64, r0 = blockIdx.y * 64;
  int tx = threadIdx.x & 63, ty = threadIdx.x >> 6;
#pragma unroll
  for (int i = 0; i < 16; ++i) {
    int r = ty * 16 + i;
    tile[r][tx] = f2bf(src[(size_t)(r0 + r) * C + c0 + tx]);
  }
  __syncthreads();
#pragma unroll
  for (int i = 0; i < 16; ++i) {
    int c = ty * 16 + i;
    dst[(size_t)(c0 + c) * R + r0 + tx] = tile[tx][c];
  }
}

// ---------------------------------------------------------------- GEMM core (128x128, 4 waves)
// (verified: global_load_lds w=16, linear LDS dest, source-side XOR chunk
//  swizzle, one barrier per K-step) -- used by proj (grid 512 -> 3 blk/CU).
__device__ __forceinline__ void gemm_core(const unsigned short* __restrict__ A,
                                          const unsigned short* __restrict__ Bt,
                                          int K, int m0, int n0,
                                          unsigned short* sm, f32x4 acc[4][4]) {
  const int t = threadIdx.x;
  const int w = t >> 6, l = t & 63;
  const int wm = w >> 1, wn = w & 1;
  const int lo = l & 15, hi = l >> 4;

  const int ci0 = w * 64 + l, ci1 = ci0 + 256;
  const int rA0 = ci0 >> 2, cA0 = (ci0 & 3) ^ ((rA0 >> 1) & 3);
  const int rA1 = ci1 >> 2, cA1 = (ci1 & 3) ^ ((rA1 >> 1) & 3);
  const unsigned short* gA0 = A  + (size_t)(m0 + rA0) * K + cA0 * 8;
  const unsigned short* gA1 = A  + (size_t)(m0 + rA1) * K + cA1 * 8;
  const unsigned short* gB0 = Bt + (size_t)(n0 + rA0) * K + cA0 * 8;
  const unsigned short* gB1 = Bt + (size_t)(n0 + rA1) * K + cA1 * 8;
  const int ldsA0 = (w * 64) * 8;
  const int ldsA1 = (256 + w * 64) * 8;

#pragma unroll
  for (int m = 0; m < 4; ++m)
#pragma unroll
    for (int n = 0; n < 4; ++n)
      acc[m][n] = (f32x4){0.f, 0.f, 0.f, 0.f};

  const int NT = K >> 5;  // BK = 32

  {
    unsigned short* b = sm;
    GLDS16(gA0, b + ldsA0);
    GLDS16(gA1, b + ldsA1);
    GLDS16(gB0, b + 4096 + ldsA0);
    GLDS16(gB1, b + 4096 + ldsA1);
  }

  for (int kt = 0; kt < NT; ++kt) {
    __syncthreads();
    if (kt + 1 < NT) {
      unsigned short* b = sm + ((kt + 1) & 1) * 8192;
      const int ko = (kt + 1) << 5;
      GLDS16(gA0 + ko, b + ldsA0);
      GLDS16(gA1 + ko, b + ldsA1);
      GLDS16(gB0 + ko, b + 4096 + ldsA0);
      GLDS16(gB1 + ko, b + 4096 + ldsA1);
    }
    const unsigned short* Ab = sm + (kt & 1) * 8192;
    const unsigned short* Bb = Ab + 4096;
    s16x8 af[4], bfr[4];
#pragma unroll
    for (int m = 0; m < 4; ++m) {
      int row = wm * 64 + m * 16 + lo;
      af[m] = *(const s16x8*)(Ab + row * 32 + ((hi ^ ((row >> 1) & 3)) << 3));
    }
#pragma unroll
    for (int n = 0; n < 4; ++n) {
      int row = wn * 64 + n * 16 + lo;
      bfr[n] = *(const s16x8*)(Bb + row * 32 + ((hi ^ ((row >> 1) & 3)) << 3));
    }
    __builtin_amdgcn_s_setprio(1);
#pragma unroll
    for (int m = 0; m < 4; ++m)
#pragma unroll
      for (int n = 0; n < 4; ++n)
        acc[m][n] = __builtin_amdgcn_mfma_f32_16x16x32_bf16(af[m], bfr[n], acc[m][n], 0, 0, 0);
    __builtin_amdgcn_s_setprio(0);
  }
}

// ------------------------------------------------------- 256x128 GEMM core
// 8 waves (512 thr), BK=32 (round-14 verified) -- used by qkv (768 blocks).
__device__ __forceinline__ void gemm256_core(const unsigned short* __restrict__ A,
                                             const unsigned short* __restrict__ Bt,
                                             int m0, int n0,
                                             unsigned short* sm, f32x4 acc[4][4]) {
  const int K = 1024;
  const int t = threadIdx.x;
  const int w = t >> 6, l = t & 63;
  const int wm = w >> 1, wn = w & 1;
  const int lo = l & 15, hi = l >> 4;

  const int rA0 = t >> 2,         cA0 = (t & 3) ^ ((rA0 >> 1) & 3);
  const int ci1 = t + 512;
  const int rA1 = ci1 >> 2,       cA1 = (ci1 & 3) ^ ((rA1 >> 1) & 3);
  const int rB  = t >> 2,         cB  = (t & 3) ^ ((rB >> 1) & 3);
  const unsigned short* gA0 = A  + (size_t)(m0 + rA0) * K + cA0 * 8;
  const unsigned short* gA1 = A  + (size_t)(m0 + rA1) * K + cA1 * 8;
  const unsigned short* gB  = Bt + (size_t)(n0 + rB)  * K + cB  * 8;
  const int ldsA0 = (w * 64) * 8;
  const int ldsA1 = (512 + w * 64) * 8;
  const int ldsB  = 8192 + (w * 64) * 8;

#pragma unroll
  for (int m = 0; m < 4; ++m)
#pragma unroll
    for (int n = 0; n < 4; ++n)
      acc[m][n] = (f32x4){0.f, 0.f, 0.f, 0.f};

  const int NT = K >> 5;  // 32 K-steps
  {
    unsigned short* b = sm;
    GLDS16(gA0, b + ldsA0);
    GLDS16(gA1, b + ldsA1);
    GLDS16(gB,  b + ldsB);
  }

  for (int kt = 0; kt < NT; ++kt) {
    __syncthreads();
    if (kt + 1 < NT) {
      unsigned short* b = sm + ((kt + 1) & 1) * 12288;
      const int ko = (kt + 1) << 5;
      GLDS16(gA0 + ko, b + ldsA0);
      GLDS16(gA1 + ko, b + ldsA1);
      GLDS16(gB  + ko, b + ldsB);
    }
    const unsigned short* Ab = sm + (kt & 1) * 12288;
    const unsigned short* Bb = Ab + 8192;
    s16x8 af[4], bfr[4];
#pragma unroll
    for (int m = 0; m < 4; ++m) {
      int row = wm * 64 + m * 16 + lo;       // 0..255
      af[m] = *(const s16x8*)(Ab + row * 32 + ((hi ^ ((row >> 1) & 3)) << 3));
    }
#pragma unroll
    for (int n = 0; n < 4; ++n) {
      int row = wn * 64 + n * 16 + lo;       // 0..127
      bfr[n] = *(const s16x8*)(Bb + row * 32 + ((hi ^ ((row >> 1) & 3)) << 3));
    }
    __builtin_amdgcn_s_setprio(1);
#pragma unroll
    for (int m = 0; m < 4; ++m)
#pragma unroll
      for (int n = 0; n < 4; ++n)
        acc[m][n] = __builtin_amdgcn_mfma_f32_16x16x32_bf16(af[m], bfr[n], acc[m][n], 0, 0, 0);
    __builtin_amdgcn_s_setprio(0);
  }
}

// GEMM1: qkv = x @ W_attn + b ; 256x128 tile (round 14).
// Round-17: V is written DIRECTLY in transposed layout [B,H,HD,S] (Vt) --
// eliminates the k_tpose_v kernel (64 MB of HBM traffic) and the Vh buffer.
__global__ __launch_bounds__(512, 1)
void k_gemm_qkv(const unsigned short* __restrict__ A, const unsigned short* __restrict__ Bt,
                const float* __restrict__ bias,
                unsigned short* __restrict__ Qh, unsigned short* __restrict__ Kh,
                unsigned short* __restrict__ Vt) {
  __shared__ unsigned short sm[2 * 12288];   // 48KB
  const int bid = blockIdx.x;               // 0..767
  const int i = bid >> 3;                   // 0..95
  const int x = (bid & 7) * 3 + (i % 3);    // 0..23 (3 N-tiles per XCD)
  const int y = i / 3;                      // 0..31
  const int m0 = y * 256, n0 = x * 128;
  f32x4 acc[4][4];
  gemm256_core(A, Bt, m0, n0, sm, acc);
  const int t = threadIdx.x, w = t >> 6, l = t & 63;
  const int wm = w >> 1, wn = w & 1, lo = l & 15, hi = l >> 4;
#pragma unroll
  for (int m = 0; m < 4; ++m)
#pragma unroll
    for (int n = 0; n < 4; ++n) {
      int col = n0 + wn * 64 + n * 16 + lo;           // 0..3071
      float bv = bias[col];
      int sel = col >> 10, cw = col & 1023, h = cw >> 6, hd = cw & 63;
      float scl = (sel == 0) ? 0.18033688011112042f : 1.0f;  // log2(e)/8
#pragma unroll
      for (int r = 0; r < 4; ++r) {
        int row = m0 + wm * 64 + m * 16 + hi * 4 + r;  // 0..8191
        int b = row >> 11, s = row & 2047;
        unsigned short v = f2bf((acc[m][n][r] + bv) * scl);
        if (sel == 0)      Qh[(((size_t)b * H_ + h) * S_ + s) * HD_ + hd] = v;
        else if (sel == 1) Kh[(((size_t)b * H_ + h) * S_ + s) * HD_ + hd] = v;
        else               Vt[(((size_t)b * H_ + h) * HD_ + hd) * S_ + s] = v;  // transposed
      }
    }
}

// GEMM2: out = ctx @ W_proj + b ; fp32 out. 128x128 core, grid 512
// (round-15 config restored: round 16's 256-block port starved occupancy).
__global__ __launch_bounds__(256, 3)
void k_gemm_proj(const unsigned short* __restrict__ A, const unsigned short* __restrict__ Bt,
                 const float* __restrict__ bias, float* __restrict__ C, int N) {
  __shared__ unsigned short sm[2 * 8192];
  const int bid = blockIdx.x;               // 0..511
  const int x = bid & 7, y = bid >> 3;      // x: 1 per XCD; y: 0..63
  const int m0 = y * 128, n0 = x * 128;
  f32x4 acc[4][4];
  gemm_core(A, Bt, 1024, m0, n0, sm, acc);
  const int t = threadIdx.x, w = t >> 6, l = t & 63;
  const int wm = w >> 1, wn = w & 1, lo = l & 15, hi = l >> 4;
#pragma unroll
  for (int m = 0; m < 4; ++m)
#pragma unroll
    for (int n = 0; n < 4; ++n) {
      int col = n0 + wn * 64 + n * 16 + lo;
      float bv = bias[col];
#pragma unroll
      for (int r = 0; r < 4; ++r) {
        int row = m0 + wm * 64 + m * 16 + hi * 4 + r;
        C[(size_t)row * N + col] = acc[m][n][r] + bv;
      }
    }
}

// ---------------------------------------------------------------- attention
// (round-15 verified: swapped QK^T; K rows LDS-permuted -> PV A-fragment
// lane-resident after cvt_pk; G4 XOR chunk swizzle, 0 conflicts; XCD
// swizzle; (jp,31-jp) pairing; KVBLK=128; constant-shift softmax m=12;
// hoisted LDS offsets; bare v_exp_f32; per-lane partial denominator.)
__global__ __launch_bounds__(256, 2)
void k_attn(const unsigned short* __restrict__ Qh, const unsigned short* __restrict__ Kh,
            const unsigned short* __restrict__ Vt, unsigned short* __restrict__ ctx) {
  __shared__ unsigned short Kl[2 * 4096];   // [sub][slot 64][hd 64], swizzled
  __shared__ unsigned short Vl[2 * 4096];   // [sub][hd 64][kv 64],  swizzled
  const int bid = blockIdx.x;
  const int g8  = bid & 7;                  // target XCD
  const int idx = bid >> 3;                 // 0..127
  const int bh  = g8 * 8 + (idx & 7);       // 8 heads per XCD
  const int jp  = idx >> 3;                 // pair index 0..15
  const int t = threadIdx.x, w = t >> 6, l = t & 63, lo = l & 15, hi = l >> 4;
  const unsigned short* Qb = Qh + (size_t)bh * S_ * HD_;
  const unsigned short* Kb = Kh + (size_t)bh * S_ * HD_;
  const unsigned short* Vb = Vt + (size_t)bh * S_ * HD_;   // [HD][S]
  const int bb = bh >> 4, h = bh & 15;

  const int r0s = t >> 3, schunk = t & 7, r1s = r0s + 32;
  const int ks0 = ((r0s & 1) << 4) | ((r0s >> 1) & 15);            // r0s<32
  const int ks1 = 32 | ((r1s & 1) << 4) | ((r1s >> 1) & 15);
  const int kd0 = ks0 * 64 + 8 * (schunk ^ (ks0 & 7));
  const int kd1 = ks1 * 64 + 8 * (schunk ^ (ks1 & 7));
  const int vd0 = r0s * 64 + 8 * (schunk ^ (r0s & 7));
  const int vd1 = r1s * 64 + 8 * (schunk ^ (r1s & 7));
  const unsigned short* ksrc0 = Kb + r0s * HD_ + schunk * 8;          // + kv*HD_
  const unsigned short* ksrc1 = Kb + r1s * HD_ + schunk * 8;
  const unsigned short* vsrc0 = Vb + (size_t)r0s * S_ + schunk * 8;   // + kv
  const unsigned short* vsrc1 = Vb + (size_t)r1s * S_ + schunk * 8;

  const int e0  = jp + 1;                   // subtile-0 extent (64-tiles)
  const int ex1 = 32 - jp;                  // subtile-1 extent (64-tiles)
  const int nv  = (ex1 + 1) >> 1;           // 128-kv visits: 9..16

  s16x8 qf[2][2];
  int qbase[2];
  qbase[0] = 64 * jp        + w * 16;
  qbase[1] = 64 * (31 - jp) + w * 16;
#pragma unroll
  for (int g = 0; g < 2; ++g)
#pragma unroll
    for (int kk = 0; kk < 2; ++kk)
      qf[g][kk] = *(const s16x8*)(Qb + (size_t)(qbase[g] + lo) * HD_ + kk * 32 + hi * 8);

  // hoisted LDS fragment offsets (shorts); shared by K (kk) and V (c) reads
  int off_[2][4];
#pragma unroll
  for (int j = 0; j < 2; ++j)
#pragma unroll
    for (int n = 0; n < 4; ++n)
      off_[j][n] = (n * 16 + lo) * 64 + 8 * ((j * 4 + hi) ^ (lo & 7));

  f32x4 O[2][4];
#pragma unroll
  for (int g = 0; g < 2; ++g)
#pragma unroll
    for (int nh = 0; nh < 4; ++nh) O[g][nh] = (f32x4){0.f, 0.f, 0.f, 0.f};
  float lrun[2] = {0.f, 0.f};               // per-lane partial denominator
  const f32x4 fz = {0.f, 0.f, 0.f, 0.f};    // persistent MFMA zero C-in

  // 64-kv body; constant-shift softmax: no cross-lane ops, no branch
  auto process = [&](int kv0, int sub, bool g0act) {
    const unsigned short* Kbuf = Kl + sub * 4096;
    const unsigned short* Vbuf = Vl + sub * 4096;
    f32x4 p[2][4];
    {                                        // kk = 0: C-in = fz
      s16x8 kf[4];
#pragma unroll
      for (int n = 0; n < 4; ++n)
        kf[n] = *(const s16x8*)&Kbuf[off_[0][n]];
      __builtin_amdgcn_s_setprio(1);
#pragma unroll
      for (int n = 0; n < 4; ++n)
        p[1][n] = __builtin_amdgcn_mfma_f32_16x16x32_bf16(kf[n], qf[1][0], fz, 0, 0, 0);
      if (g0act) {
#pragma unroll
        for (int n = 0; n < 4; ++n)
          p[0][n] = __builtin_amdgcn_mfma_f32_16x16x32_bf16(kf[n], qf[0][0], fz, 0, 0, 0);
      }
      __builtin_amdgcn_s_setprio(0);
    }
    {                                        // kk = 1: accumulate
      s16x8 kf[4];
#pragma unroll
      for (int n = 0; n < 4; ++n)
        kf[n] = *(const s16x8*)&Kbuf[off_[1][n]];
      __builtin_amdgcn_s_setprio(1);
#pragma unroll
      for (int n = 0; n < 4; ++n)
        p[1][n] = __builtin_amdgcn_mfma_f32_16x16x32_bf16(kf[n], qf[1][1], p[1][n], 0, 0, 0);
      if (g0act) {
#pragma unroll
        for (int n = 0; n < 4; ++n)
          p[0][n] = __builtin_amdgcn_mfma_f32_16x16x32_bf16(kf[n], qf[0][1], p[0][n], 0, 0, 0);
      }
      __builtin_amdgcn_s_setprio(0);
    }

    union PU { unsigned int u[4]; s16x8 s; };
    PU pa[2][2];
#pragma unroll
    for (int g = 0; g < 2; ++g) {
      if (g == 0 && !g0act) continue;      // block-uniform skip
      if (kv0 + 63 > qbase[g]) {           // wave-uniform: diagonal tile only
        const int q = qbase[g] + lo;
#pragma unroll
        for (int n = 0; n < 4; ++n)
#pragma unroll
          for (int r = 0; r < 4; ++r) {
            int kv = kv0 + 32 * (n >> 1) + 8 * hi + 2 * r + (n & 1);
            p[g][n][r] = (kv <= q) ? p[g][n][r] : -1e30f;
          }
      }
      // constant-shift softmax: e = 2^(s - 12); shift cancels in O/l
      float s0 = 0.f, s1 = 0.f, s2 = 0.f, s3 = 0.f;
#pragma unroll
      for (int n = 0; n < 4; ++n) {
        float e0_ = EXP2(p[g][n][0] - 12.0f);   // masked: exp2(-1e30)=0
        float e1_ = EXP2(p[g][n][1] - 12.0f);
        float e2_ = EXP2(p[g][n][2] - 12.0f);
        float e3_ = EXP2(p[g][n][3] - 12.0f);
        p[g][n][0] = e0_; p[g][n][1] = e1_;
        p[g][n][2] = e2_; p[g][n][3] = e3_;
        s0 += e0_; s1 += e1_; s2 += e2_; s3 += e3_;
      }
      lrun[g] += (s0 + s1) + (s2 + s3);    // per-lane partial; reduce at epilogue
#pragma unroll
      for (int c = 0; c < 2; ++c)
#pragma unroll
        for (int r = 0; r < 4; ++r) {
          unsigned int pk;
          asm("v_cvt_pk_bf16_f32 %0, %1, %2"
              : "=v"(pk) : "v"(p[g][2 * c][r]), "v"(p[g][2 * c + 1][r]));
          pa[g][c].u[r] = pk;
        }
    }

#pragma unroll
    for (int c = 0; c < 2; ++c) {
      s16x8 vf[4];
#pragma unroll
      for (int nh = 0; nh < 4; ++nh)
        vf[nh] = *(const s16x8*)&Vbuf[off_[c][nh]];
      __builtin_amdgcn_s_setprio(1);
#pragma unroll
      for (int nh = 0; nh < 4; ++nh)
        O[1][nh] = __builtin_amdgcn_mfma_f32_16x16x32_bf16(pa[1][c].s, vf[nh], O[1][nh], 0, 0, 0);
      if (g0act) {
#pragma unroll
        for (int nh = 0; nh < 4; ++nh)
          O[0][nh] = __builtin_amdgcn_mfma_f32_16x16x32_bf16(pa[0][c].s, vf[nh], O[0][nh], 0, 0, 0);
      }
      __builtin_amdgcn_s_setprio(0);
    }
  };

  // prologue: visit 0 (tiles 0,1) -> LDS
  u16x8 rk00 = *(const u16x8*)ksrc0;
  u16x8 rk01 = *(const u16x8*)ksrc1;
  u16x8 rk10 = *(const u16x8*)(ksrc0 + (size_t)64 * HD_);
  u16x8 rk11 = *(const u16x8*)(ksrc1 + (size_t)64 * HD_);
  u16x8 rv00 = *(const u16x8*)vsrc0;
  u16x8 rv01 = *(const u16x8*)vsrc1;
  u16x8 rv10 = *(const u16x8*)(vsrc0 + 64);
  u16x8 rv11 = *(const u16x8*)(vsrc1 + 64);
  *(u16x8*)&Kl[kd0] = rk00;        *(u16x8*)&Kl[kd1] = rk01;
  *(u16x8*)&Kl[4096 + kd0] = rk10; *(u16x8*)&Kl[4096 + kd1] = rk11;
  *(u16x8*)&Vl[vd0] = rv00;        *(u16x8*)&Vl[vd1] = rv01;
  *(u16x8*)&Vl[4096 + vd0] = rv10; *(u16x8*)&Vl[4096 + vd1] = rv11;
  __syncthreads();

  for (int kt = 0; kt < nv; ++kt) {
    const int base = kt * 128;
    const bool pf = (kt + 1 < nv);
    if (pf) {                              // T14: issue loads BEFORE compute
      const int nb = base + 128;
      rk00 = *(const u16x8*)(ksrc0 + (size_t)nb * HD_);
      rk01 = *(const u16x8*)(ksrc1 + (size_t)nb * HD_);
      rk10 = *(const u16x8*)(ksrc0 + (size_t)(nb + 64) * HD_);
      rk11 = *(const u16x8*)(ksrc1 + (size_t)(nb + 64) * HD_);
      rv00 = *(const u16x8*)(vsrc0 + nb);
      rv01 = *(const u16x8*)(vsrc1 + nb);
      rv10 = *(const u16x8*)(vsrc0 + nb + 64);
      rv11 = *(const u16x8*)(vsrc1 + nb + 64);
    }

    process(base, 0, 2 * kt < e0);              // sub-tile 0 (always < ex1)
    if (2 * kt + 1 < ex1)
      process(base + 64, 1, 2 * kt + 1 < e0);   // sub-tile 1

    if (pf) {                              // T14: write AFTER compute
      __syncthreads();                     // all reads of Kl/Vl done
      *(u16x8*)&Kl[kd0] = rk00;        *(u16x8*)&Kl[kd1] = rk01;
      *(u16x8*)&Kl[4096 + kd0] = rk10; *(u16x8*)&Kl[4096 + kd1] = rk11;
      *(u16x8*)&Vl[vd0] = rv00;        *(u16x8*)&Vl[vd1] = rv01;
      *(u16x8*)&Vl[4096 + vd0] = rv10; *(u16x8*)&Vl[4096 + vd1] = rv11;
      __syncthreads();                     // staged visible
    }
  }

  // epilogue: reduce per-lane lrun partials once, then store ctx bf16
#pragma unroll
  for (int g = 0; g < 2; ++g) {
    float lr = lrun[g];
    lr += __shfl_xor(lr, 16);
    lr += __shfl_xor(lr, 32);              // row sum (uniform across hi)
#pragma unroll
    for (int r = 0; r < 4; ++r) {
      float li = 1.0f / __shfl(lr, 4 * hi + r);
      int qg = qbase[g] + 4 * hi + r;
#pragma unroll
      for (int nh = 0; nh < 4; ++nh) {
        int hd = nh * 16 + lo;
        ctx[(((size_t)(bb * S_ + qg)) * H_ + h) * HD_ + hd] = f2bf(O[g][nh][r] * li);
      }
    }
  }
}

// ---------------------------------------------------------------- launch
extern "C" void kernel_launch(void* const* d_in, const int* in_sizes, int n_in,
                              void* d_out, int out_size, void* d_ws, size_t ws_size,
                              hipStream_t stream) {
  const float* x      = (const float*)d_in[0];
  const float* W_attn = (const float*)d_in[1];
  const float* b_attn = (const float*)d_in[2];
  const float* W_proj = (const float*)d_in[3];
  const float* b_proj = (const float*)d_in[4];
  float* out = (float*)d_out;

  char* ws = (char*)d_ws;
  size_t off = 0;
  auto alloc = [&](size_t bytes) {
    char* p = ws + off;
    off += (bytes + 255) & ~(size_t)255;
    return p;
  };
  unsigned short* xb  = (unsigned short*)alloc((size_t)8192 * 1024 * 2);
  unsigned short* Wta = (unsigned short*)alloc((size_t)3072 * 1024 * 2);
  unsigned short* Wtp = (unsigned short*)alloc((size_t)1024 * 1024 * 2);
  unsigned short* Qh  = (unsigned short*)alloc((size_t)64 * 2048 * 64 * 2);
  unsigned short* Kh  = (unsigned short*)alloc((size_t)64 * 2048 * 64 * 2);
  unsigned short* Vt  = (unsigned short*)alloc((size_t)64 * 2048 * 64 * 2);
  unsigned short* ctx = (unsigned short*)alloc((size_t)8192 * 1024 * 2);

  k_cvt<<<dim3(2048), dim3(256), 0, stream>>>(x, xb, (8192 * 1024) / 4);
  k_tpose_cvt<<<dim3(48, 16), dim3(256), 0, stream>>>(W_attn, Wta, 1024, 3072);
  k_tpose_cvt<<<dim3(16, 16), dim3(256), 0, stream>>>(W_proj, Wtp, 1024, 1024);
  k_gemm_qkv<<<dim3(768), dim3(512), 0, stream>>>(xb, Wta, b_attn, Qh, Kh, Vt);
  k_attn<<<dim3(1024), dim3(256), 0, stream>>>(Qh, Kh, Vt, ctx);
  k_gemm_proj<<<dim3(512), dim3(256), 0, stream>>>(ctx, Wtp, b_proj, out, 1024);
}

// Round 18
// 165.651 us; speedup vs baseline: 1.1932x; 1.1932x over previous
//
#include <hip/hip_runtime.h>
#include <hip/hip_bf16.h>
#include <stdint.h>

// Problem constants: B=4, S=2048, D=1024, H=16, HD=64
#define B_  4
#define S_  2048
#define D_  1024
#define H_  16
#define HD_ 64

typedef __attribute__((ext_vector_type(8))) short          s16x8;   // MFMA A/B frag (8 bf16)
typedef __attribute__((ext_vector_type(4))) float          f32x4;   // MFMA C/D frag
typedef __attribute__((ext_vector_type(8))) unsigned short u16x8;   // 16B bf16 chunk

__device__ __forceinline__ unsigned short f2bf(float f) {
  union { float f; unsigned int u; } v; v.f = f;
  unsigned int u = v.u;
  u += 0x7fffu + ((u >> 16) & 1u);       // RNE
  return (unsigned short)(u >> 16);
}

// bare v_exp_f32 (2^x); exp2f without -ffast-math is OCML guarded code.
#if __has_builtin(__builtin_amdgcn_exp2f)
#define EXP2(x) __builtin_amdgcn_exp2f(x)
#else
#define EXP2(x) exp2f(x)
#endif

// async global->LDS, 16B per lane; LDS dest = wave-uniform base + lane*16
#define GLDS16(g, l)                                                           \
  __builtin_amdgcn_global_load_lds(                                            \
      (const __attribute__((address_space(1))) void*)(g),                      \
      (__attribute__((address_space(3))) void*)(l), 16, 0, 0)

// ---------------------------------------------------------------- converts
__global__ void k_cvt(const float* __restrict__ src, unsigned short* __restrict__ dst, int n4) {
  int i = blockIdx.x * blockDim.x + threadIdx.x;
  int stride = gridDim.x * blockDim.x;
  for (int j = i; j < n4; j += stride) {
    float4 v = reinterpret_cast<const float4*>(src)[j];
    ushort4 o;
    o.x = f2bf(v.x); o.y = f2bf(v.y); o.z = f2bf(v.z); o.w = f2bf(v.w);
    reinterpret_cast<ushort4*>(dst)[j] = o;
  }
}

// fp32 [R][C] -> bf16 [C][R]   (weights -> B^T layout for gemm-BT)
__global__ void k_tpose_cvt(const float* __restrict__ src, unsigned short* __restrict__ dst,
                            int R, int C) {
  __shared__ unsigned short tile[64][72];
  int c0 = blockIdx.x * 64, r0 = blockIdx.y * 64;
  int tx = threadIdx.x & 63, ty = threadIdx.x >> 6;
#pragma unroll
  for (int i = 0; i < 16; ++i) {
    int r = ty * 16 + i;
    tile[r][tx] = f2bf(src[(size_t)(r0 + r) * C + c0 + tx]);
  }
  __syncthreads();
#pragma unroll
  for (int i = 0; i < 16; ++i) {
    int c = ty * 16 + i;
    dst[(size_t)(c0 + c) * R + r0 + tx] = tile[tx][c];
  }
}

// bf16 V [BH][S][HD] -> Vt [BH][HD][S]
__global__ void k_tpose_v(const unsigned short* __restrict__ src, unsigned short* __restrict__ dst) {
  __shared__ unsigned short tile[64][72];
  int s0 = blockIdx.x * 64, bh = blockIdx.y;
  int tx = threadIdx.x & 63, ty = threadIdx.x >> 6;
  const unsigned short* sb = src + (size_t)bh * S_ * HD_;
  unsigned short*       db = dst + (size_t)bh * S_ * HD_;
#pragma unroll
  for (int i = 0; i < 16; ++i) {
    int r = ty * 16 + i;
    tile[r][tx] = sb[(size_t)(s0 + r) * HD_ + tx];
  }
  __syncthreads();
#pragma unroll
  for (int i = 0; i < 16; ++i) {
    int hd = ty * 16 + i;
    db[(size_t)hd * S_ + s0 + tx] = tile[tx][hd];
  }
}

// ---------------------------------------------------------------- GEMM core (128x128, 4 waves)
__device__ __forceinline__ void gemm_core(const unsigned short* __restrict__ A,
                                          const unsigned short* __restrict__ Bt,
                                          int K, int m0, int n0,
                                          unsigned short* sm, f32x4 acc[4][4]) {
  const int t = threadIdx.x;
  const int w = t >> 6, l = t & 63;
  const int wm = w >> 1, wn = w & 1;
  const int lo = l & 15, hi = l >> 4;

  const int ci0 = w * 64 + l, ci1 = ci0 + 256;
  const int rA0 = ci0 >> 2, cA0 = (ci0 & 3) ^ ((rA0 >> 1) & 3);
  const int rA1 = ci1 >> 2, cA1 = (ci1 & 3) ^ ((rA1 >> 1) & 3);
  const unsigned short* gA0 = A  + (size_t)(m0 + rA0) * K + cA0 * 8;
  const unsigned short* gA1 = A  + (size_t)(m0 + rA1) * K + cA1 * 8;
  const unsigned short* gB0 = Bt + (size_t)(n0 + rA0) * K + cA0 * 8;
  const unsigned short* gB1 = Bt + (size_t)(n0 + rA1) * K + cA1 * 8;
  const int ldsA0 = (w * 64) * 8;
  const int ldsA1 = (256 + w * 64) * 8;

#pragma unroll
  for (int m = 0; m < 4; ++m)
#pragma unroll
    for (int n = 0; n < 4; ++n)
      acc[m][n] = (f32x4){0.f, 0.f, 0.f, 0.f};

  const int NT = K >> 5;  // BK = 32

  {
    unsigned short* b = sm;
    GLDS16(gA0, b + ldsA0);
    GLDS16(gA1, b + ldsA1);
    GLDS16(gB0, b + 4096 + ldsA0);
    GLDS16(gB1, b + 4096 + ldsA1);
  }

  for (int kt = 0; kt < NT; ++kt) {
    __syncthreads();
    if (kt + 1 < NT) {
      unsigned short* b = sm + ((kt + 1) & 1) * 8192;
      const int ko = (kt + 1) << 5;
      GLDS16(gA0 + ko, b + ldsA0);
      GLDS16(gA1 + ko, b + ldsA1);
      GLDS16(gB0 + ko, b + 4096 + ldsA0);
      GLDS16(gB1 + ko, b + 4096 + ldsA1);
    }
    const unsigned short* Ab = sm + (kt & 1) * 8192;
    const unsigned short* Bb = Ab + 4096;
    s16x8 af[4], bfr[4];
#pragma unroll
    for (int m = 0; m < 4; ++m) {
      int row = wm * 64 + m * 16 + lo;
      af[m] = *(const s16x8*)(Ab + row * 32 + ((hi ^ ((row >> 1) & 3)) << 3));
    }
#pragma unroll
    for (int n = 0; n < 4; ++n) {
      int row = wn * 64 + n * 16 + lo;
      bfr[n] = *(const s16x8*)(Bb + row * 32 + ((hi ^ ((row >> 1) & 3)) << 3));
    }
    __builtin_amdgcn_s_setprio(1);
#pragma unroll
    for (int m = 0; m < 4; ++m)
#pragma unroll
      for (int n = 0; n < 4; ++n)
        acc[m][n] = __builtin_amdgcn_mfma_f32_16x16x32_bf16(af[m], bfr[n], acc[m][n], 0, 0, 0);
    __builtin_amdgcn_s_setprio(0);
  }
}

// ------------------------------------------------------- 256x128 GEMM core
// 8 waves (512 thr), BK=32, 2-phase, global_load_lds w=16, linear LDS dest,
// source-side XOR chunk swizzle (round-14 verified). wm = w>>1, wn = w&1.
__device__ __forceinline__ void gemm256_core(const unsigned short* __restrict__ A,
                                             const unsigned short* __restrict__ Bt,
                                             int m0, int n0,
                                             unsigned short* sm, f32x4 acc[4][4]) {
  const int K = 1024;
  const int t = threadIdx.x;
  const int w = t >> 6, l = t & 63;
  const int wm = w >> 1, wn = w & 1;
  const int lo = l & 15, hi = l >> 4;

  const int rA0 = t >> 2,         cA0 = (t & 3) ^ ((rA0 >> 1) & 3);
  const int ci1 = t + 512;
  const int rA1 = ci1 >> 2,       cA1 = (ci1 & 3) ^ ((rA1 >> 1) & 3);
  const int rB  = t >> 2,         cB  = (t & 3) ^ ((rB >> 1) & 3);
  const unsigned short* gA0 = A  + (size_t)(m0 + rA0) * K + cA0 * 8;
  const unsigned short* gA1 = A  + (size_t)(m0 + rA1) * K + cA1 * 8;
  const unsigned short* gB  = Bt + (size_t)(n0 + rB)  * K + cB  * 8;
  const int ldsA0 = (w * 64) * 8;
  const int ldsA1 = (512 + w * 64) * 8;
  const int ldsB  = 8192 + (w * 64) * 8;

#pragma unroll
  for (int m = 0; m < 4; ++m)
#pragma unroll
    for (int n = 0; n < 4; ++n)
      acc[m][n] = (f32x4){0.f, 0.f, 0.f, 0.f};

  const int NT = K >> 5;  // 32 K-steps
  {
    unsigned short* b = sm;
    GLDS16(gA0, b + ldsA0);
    GLDS16(gA1, b + ldsA1);
    GLDS16(gB,  b + ldsB);
  }

  for (int kt = 0; kt < NT; ++kt) {
    __syncthreads();
    if (kt + 1 < NT) {
      unsigned short* b = sm + ((kt + 1) & 1) * 12288;
      const int ko = (kt + 1) << 5;
      GLDS16(gA0 + ko, b + ldsA0);
      GLDS16(gA1 + ko, b + ldsA1);
      GLDS16(gB  + ko, b + ldsB);
    }
    const unsigned short* Ab = sm + (kt & 1) * 12288;
    const unsigned short* Bb = Ab + 8192;
    s16x8 af[4], bfr[4];
#pragma unroll
    for (int m = 0; m < 4; ++m) {
      int row = wm * 64 + m * 16 + lo;       // 0..255
      af[m] = *(const s16x8*)(Ab + row * 32 + ((hi ^ ((row >> 1) & 3)) << 3));
    }
#pragma unroll
    for (int n = 0; n < 4; ++n) {
      int row = wn * 64 + n * 16 + lo;       // 0..127
      bfr[n] = *(const s16x8*)(Bb + row * 32 + ((hi ^ ((row >> 1) & 3)) << 3));
    }
    __builtin_amdgcn_s_setprio(1);
#pragma unroll
    for (int m = 0; m < 4; ++m)
#pragma unroll
      for (int n = 0; n < 4; ++n)
        acc[m][n] = __builtin_amdgcn_mfma_f32_16x16x32_bf16(af[m], bfr[n], acc[m][n], 0, 0, 0);
    __builtin_amdgcn_s_setprio(0);
  }
}

// GEMM1: qkv = x @ W_attn + b ; 256x128 tile (round 14).
__global__ __launch_bounds__(512, 1)
void k_gemm_qkv(const unsigned short* __restrict__ A, const unsigned short* __restrict__ Bt,
                const float* __restrict__ bias,
                unsigned short* __restrict__ Qh, unsigned short* __restrict__ Kh,
                unsigned short* __restrict__ Vh) {
  __shared__ unsigned short sm[2 * 12288];   // 48KB
  const int bid = blockIdx.x;               // 0..767
  const int i = bid >> 3;                   // 0..95
  const int x = (bid & 7) * 3 + (i % 3);    // 0..23 (3 N-tiles per XCD)
  const int y = i / 3;                      // 0..31
  const int m0 = y * 256, n0 = x * 128;
  f32x4 acc[4][4];
  gemm256_core(A, Bt, m0, n0, sm, acc);
  const int t = threadIdx.x, w = t >> 6, l = t & 63;
  const int wm = w >> 1, wn = w & 1, lo = l & 15, hi = l >> 4;
  // epilogue: scatter into Q/K/V [B,H,S,HD] bf16 (Q pre-scaled by log2(e)/8)
#pragma unroll
  for (int m = 0; m < 4; ++m)
#pragma unroll
    for (int n = 0; n < 4; ++n) {
      int col = n0 + wn * 64 + n * 16 + lo;           // 0..3071
      float bv = bias[col];
      int sel = col >> 10, cw = col & 1023, h = cw >> 6, hd = cw & 63;
      float scl = (sel == 0) ? 0.18033688011112042f : 1.0f;  // log2(e)/8
      unsigned short* dst = (sel == 0) ? Qh : ((sel == 1) ? Kh : Vh);
#pragma unroll
      for (int r = 0; r < 4; ++r) {
        int row = m0 + wm * 64 + m * 16 + hi * 4 + r;  // 0..8191
        int b = row >> 11, s = row & 2047;
        dst[(((size_t)b * H_ + h) * S_ + s) * HD_ + hd] = f2bf((acc[m][n][r] + bv) * scl);
      }
    }
}

// GEMM2: out = ctx @ W_proj + b ; fp32 out. 128x128 core, grid 512.
__global__ __launch_bounds__(256, 3)
void k_gemm_proj(const unsigned short* __restrict__ A, const unsigned short* __restrict__ Bt,
                 const float* __restrict__ bias, float* __restrict__ C, int N) {
  __shared__ unsigned short sm[2 * 8192];
  const int bid = blockIdx.x;               // 0..511
  const int x = bid & 7, y = bid >> 3;      // x: 1 per XCD; y: 0..63
  const int m0 = y * 128, n0 = x * 128;
  f32x4 acc[4][4];
  gemm_core(A, Bt, 1024, m0, n0, sm, acc);
  const int t = threadIdx.x, w = t >> 6, l = t & 63;
  const int wm = w >> 1, wn = w & 1, lo = l & 15, hi = l >> 4;
#pragma unroll
  for (int m = 0; m < 4; ++m)
#pragma unroll
    for (int n = 0; n < 4; ++n) {
      int col = n0 + wn * 64 + n * 16 + lo;
      float bv = bias[col];
#pragma unroll
      for (int r = 0; r < 4; ++r) {
        int row = m0 + wm * 64 + m * 16 + hi * 4 + r;
        C[(size_t)row * N + col] = acc[m][n][r] + bv;
      }
    }
}

// ---------------------------------------------------------------- attention
// (round-15 verified: swapped QK^T; K rows LDS-permuted -> PV A-fragment
// lane-resident after cvt_pk; G4 XOR chunk swizzle, 0 conflicts; XCD
// swizzle; (jp,31-jp) pairing; KVBLK=128; constant-shift softmax m=12
// (exact, shift cancels in O/l); hoisted LDS offsets; bare v_exp_f32;
// 4-way sum partials; per-lane partial denominator, epilogue reduce.)
__global__ __launch_bounds__(256, 2)
void k_attn(const unsigned short* __restrict__ Qh, const unsigned short* __restrict__ Kh,
            const unsigned short* __restrict__ Vt, unsigned short* __restrict__ ctx) {
  __shared__ unsigned short Kl[2 * 4096];   // [sub][slot 64][hd 64], swizzled
  __shared__ unsigned short Vl[2 * 4096];   // [sub][hd 64][kv 64],  swizzled
  const int bid = blockIdx.x;
  const int g8  = bid & 7;                  // target XCD
  const int idx = bid >> 3;                 // 0..127
  const int bh  = g8 * 8 + (idx & 7);       // 8 heads per XCD
  const int jp  = idx >> 3;                 // pair index 0..15
  const int t = threadIdx.x, w = t >> 6, l = t & 63, lo = l & 15, hi = l >> 4;
  const unsigned short* Qb = Qh + (size_t)bh * S_ * HD_;
  const unsigned short* Kb = Kh + (size_t)bh * S_ * HD_;
  const unsigned short* Vb = Vt + (size_t)bh * S_ * HD_;   // [HD][S]
  const int bb = bh >> 4, h = bh & 15;

  const int r0s = t >> 3, schunk = t & 7, r1s = r0s + 32;
  const int ks0 = ((r0s & 1) << 4) | ((r0s >> 1) & 15);            // r0s<32
  const int ks1 = 32 | ((r1s & 1) << 4) | ((r1s >> 1) & 15);
  const int kd0 = ks0 * 64 + 8 * (schunk ^ (ks0 & 7));
  const int kd1 = ks1 * 64 + 8 * (schunk ^ (ks1 & 7));
  const int vd0 = r0s * 64 + 8 * (schunk ^ (r0s & 7));
  const int vd1 = r1s * 64 + 8 * (schunk ^ (r1s & 7));
  const unsigned short* ksrc0 = Kb + r0s * HD_ + schunk * 8;          // + kv*HD_
  const unsigned short* ksrc1 = Kb + r1s * HD_ + schunk * 8;
  const unsigned short* vsrc0 = Vb + (size_t)r0s * S_ + schunk * 8;   // + kv
  const unsigned short* vsrc1 = Vb + (size_t)r1s * S_ + schunk * 8;

  const int e0  = jp + 1;                   // subtile-0 extent (64-tiles)
  const int ex1 = 32 - jp;                  // subtile-1 extent (64-tiles)
  const int nv  = (ex1 + 1) >> 1;           // 128-kv visits: 9..16

  s16x8 qf[2][2];
  int qbase[2];
  qbase[0] = 64 * jp        + w * 16;
  qbase[1] = 64 * (31 - jp) + w * 16;
#pragma unroll
  for (int g = 0; g < 2; ++g)
#pragma unroll
    for (int kk = 0; kk < 2; ++kk)
      qf[g][kk] = *(const s16x8*)(Qb + (size_t)(qbase[g] + lo) * HD_ + kk * 32 + hi * 8);

  // hoisted LDS fragment offsets (shorts); shared by K (kk) and V (c) reads
  int off_[2][4];
#pragma unroll
  for (int j = 0; j < 2; ++j)
#pragma unroll
    for (int n = 0; n < 4; ++n)
      off_[j][n] = (n * 16 + lo) * 64 + 8 * ((j * 4 + hi) ^ (lo & 7));

  f32x4 O[2][4];
#pragma unroll
  for (int g = 0; g < 2; ++g)
#pragma unroll
    for (int nh = 0; nh < 4; ++nh) O[g][nh] = (f32x4){0.f, 0.f, 0.f, 0.f};
  float lrun[2] = {0.f, 0.f};               // per-lane partial denominator
  const f32x4 fz = {0.f, 0.f, 0.f, 0.f};    // persistent MFMA zero C-in

  // 64-kv body; constant-shift softmax: no cross-lane ops, no branch
  auto process = [&](int kv0, int sub, bool g0act) {
    const unsigned short* Kbuf = Kl + sub * 4096;
    const unsigned short* Vbuf = Vl + sub * 4096;
    f32x4 p[2][4];
    {                                        // kk = 0: C-in = fz
      s16x8 kf[4];
#pragma unroll
      for (int n = 0; n < 4; ++n)
        kf[n] = *(const s16x8*)&Kbuf[off_[0][n]];
      __builtin_amdgcn_s_setprio(1);
#pragma unroll
      for (int n = 0; n < 4; ++n)
        p[1][n] = __builtin_amdgcn_mfma_f32_16x16x32_bf16(kf[n], qf[1][0], fz, 0, 0, 0);
      if (g0act) {
#pragma unroll
        for (int n = 0; n < 4; ++n)
          p[0][n] = __builtin_amdgcn_mfma_f32_16x16x32_bf16(kf[n], qf[0][0], fz, 0, 0, 0);
      }
      __builtin_amdgcn_s_setprio(0);
    }
    {                                        // kk = 1: accumulate
      s16x8 kf[4];
#pragma unroll
      for (int n = 0; n < 4; ++n)
        kf[n] = *(const s16x8*)&Kbuf[off_[1][n]];
      __builtin_amdgcn_s_setprio(1);
#pragma unroll
      for (int n = 0; n < 4; ++n)
        p[1][n] = __builtin_amdgcn_mfma_f32_16x16x32_bf16(kf[n], qf[1][1], p[1][n], 0, 0, 0);
      if (g0act) {
#pragma unroll
        for (int n = 0; n < 4; ++n)
          p[0][n] = __builtin_amdgcn_mfma_f32_16x16x32_bf16(kf[n], qf[0][1], p[0][n], 0, 0, 0);
      }
      __builtin_amdgcn_s_setprio(0);
    }

    union PU { unsigned int u[4]; s16x8 s; };
    PU pa[2][2];
#pragma unroll
    for (int g = 0; g < 2; ++g) {
      if (g == 0 && !g0act) continue;      // block-uniform skip
      if (kv0 + 63 > qbase[g]) {           // wave-uniform: diagonal tile only
        const int q = qbase[g] + lo;
#pragma unroll
        for (int n = 0; n < 4; ++n)
#pragma unroll
          for (int r = 0; r < 4; ++r) {
            int kv = kv0 + 32 * (n >> 1) + 8 * hi + 2 * r + (n & 1);
            p[g][n][r] = (kv <= q) ? p[g][n][r] : -1e30f;
          }
      }
      // constant-shift softmax: e = 2^(s - 12); shift cancels in O/l
      float s0 = 0.f, s1 = 0.f, s2 = 0.f, s3 = 0.f;
#pragma unroll
      for (int n = 0; n < 4; ++n) {
        float e0_ = EXP2(p[g][n][0] - 12.0f);   // masked: exp2(-1e30)=0
        float e1_ = EXP2(p[g][n][1] - 12.0f);
        float e2_ = EXP2(p[g][n][2] - 12.0f);
        float e3_ = EXP2(p[g][n][3] - 12.0f);
        p[g][n][0] = e0_; p[g][n][1] = e1_;
        p[g][n][2] = e2_; p[g][n][3] = e3_;
        s0 += e0_; s1 += e1_; s2 += e2_; s3 += e3_;
      }
      lrun[g] += (s0 + s1) + (s2 + s3);    // per-lane partial; reduce at epilogue
#pragma unroll
      for (int c = 0; c < 2; ++c)
#pragma unroll
        for (int r = 0; r < 4; ++r) {
          unsigned int pk;
          asm("v_cvt_pk_bf16_f32 %0, %1, %2"
              : "=v"(pk) : "v"(p[g][2 * c][r]), "v"(p[g][2 * c + 1][r]));
          pa[g][c].u[r] = pk;
        }
    }

#pragma unroll
    for (int c = 0; c < 2; ++c) {
      s16x8 vf[4];
#pragma unroll
      for (int nh = 0; nh < 4; ++nh)
        vf[nh] = *(const s16x8*)&Vbuf[off_[c][nh]];
      __builtin_amdgcn_s_setprio(1);
#pragma unroll
      for (int nh = 0; nh < 4; ++nh)
        O[1][nh] = __builtin_amdgcn_mfma_f32_16x16x32_bf16(pa[1][c].s, vf[nh], O[1][nh], 0, 0, 0);
      if (g0act) {
#pragma unroll
        for (int nh = 0; nh < 4; ++nh)
          O[0][nh] = __builtin_amdgcn_mfma_f32_16x16x32_bf16(pa[0][c].s, vf[nh], O[0][nh], 0, 0, 0);
      }
      __builtin_amdgcn_s_setprio(0);
    }
  };

  // prologue: visit 0 (tiles 0,1) -> LDS
  u16x8 rk00 = *(const u16x8*)ksrc0;
  u16x8 rk01 = *(const u16x8*)ksrc1;
  u16x8 rk10 = *(const u16x8*)(ksrc0 + (size_t)64 * HD_);
  u16x8 rk11 = *(const u16x8*)(ksrc1 + (size_t)64 * HD_);
  u16x8 rv00 = *(const u16x8*)vsrc0;
  u16x8 rv01 = *(const u16x8*)vsrc1;
  u16x8 rv10 = *(const u16x8*)(vsrc0 + 64);
  u16x8 rv11 = *(const u16x8*)(vsrc1 + 64);
  *(u16x8*)&Kl[kd0] = rk00;        *(u16x8*)&Kl[kd1] = rk01;
  *(u16x8*)&Kl[4096 + kd0] = rk10; *(u16x8*)&Kl[4096 + kd1] = rk11;
  *(u16x8*)&Vl[vd0] = rv00;        *(u16x8*)&Vl[vd1] = rv01;
  *(u16x8*)&Vl[4096 + vd0] = rv10; *(u16x8*)&Vl[4096 + vd1] = rv11;
  __syncthreads();

  for (int kt = 0; kt < nv; ++kt) {
    const int base = kt * 128;
    const bool pf = (kt + 1 < nv);
    if (pf) {                              // T14: issue loads BEFORE compute
      const int nb = base + 128;
      rk00 = *(const u16x8*)(ksrc0 + (size_t)nb * HD_);
      rk01 = *(const u16x8*)(ksrc1 + (size_t)nb * HD_);
      rk10 = *(const u16x8*)(ksrc0 + (size_t)(nb + 64) * HD_);
      rk11 = *(const u16x8*)(ksrc1 + (size_t)(nb + 64) * HD_);
      rv00 = *(const u16x8*)(vsrc0 + nb);
      rv01 = *(const u16x8*)(vsrc1 + nb);
      rv10 = *(const u16x8*)(vsrc0 + nb + 64);
      rv11 = *(const u16x8*)(vsrc1 + nb + 64);
    }

    process(base, 0, 2 * kt < e0);              // sub-tile 0 (always < ex1)
    if (2 * kt + 1 < ex1)
      process(base + 64, 1, 2 * kt + 1 < e0);   // sub-tile 1

    if (pf) {                              // T14: write AFTER compute
      __syncthreads();                     // all reads of Kl/Vl done
      *(u16x8*)&Kl[kd0] = rk00;        *(u16x8*)&Kl[kd1] = rk01;
      *(u16x8*)&Kl[4096 + kd0] = rk10; *(u16x8*)&Kl[4096 + kd1] = rk11;
      *(u16x8*)&Vl[vd0] = rv00;        *(u16x8*)&Vl[vd1] = rv01;
      *(u16x8*)&Vl[4096 + vd0] = rv10; *(u16x8*)&Vl[4096 + vd1] = rv11;
      __syncthreads();                     // staged visible
    }
  }

  // epilogue: reduce per-lane lrun partials once, then store ctx bf16
#pragma unroll
  for (int g = 0; g < 2; ++g) {
    float lr = lrun[g];
    lr += __shfl_xor(lr, 16);
    lr += __shfl_xor(lr, 32);              // row sum (uniform across hi)
#pragma unroll
    for (int r = 0; r < 4; ++r) {
      float li = 1.0f / __shfl(lr, 4 * hi + r);
      int qg = qbase[g] + 4 * hi + r;
#pragma unroll
      for (int nh = 0; nh < 4; ++nh) {
        int hd = nh * 16 + lo;
        ctx[(((size_t)(bb * S_ + qg)) * H_ + h) * HD_ + hd] = f2bf(O[g][nh][r] * li);
      }
    }
  }
}

// ---------------------------------------------------------------- launch
extern "C" void kernel_launch(void* const* d_in, const int* in_sizes, int n_in,
                              void* d_out, int out_size, void* d_ws, size_t ws_size,
                              hipStream_t stream) {
  const float* x      = (const float*)d_in[0];
  const float* W_attn = (const float*)d_in[1];
  const float* b_attn = (const float*)d_in[2];
  const float* W_proj = (const float*)d_in[3];
  const float* b_proj = (const float*)d_in[4];
  float* out = (float*)d_out;

  char* ws = (char*)d_ws;
  size_t off = 0;
  auto alloc = [&](size_t bytes) {
    char* p = ws + off;
    off += (bytes + 255) & ~(size_t)255;
    return p;
  };
  unsigned short* xb  = (unsigned short*)alloc((size_t)8192 * 1024 * 2);
  unsigned short* Wta = (unsigned short*)alloc((size_t)3072 * 1024 * 2);
  unsigned short* Wtp = (unsigned short*)alloc((size_t)1024 * 1024 * 2);
  unsigned short* Qh  = (unsigned short*)alloc((size_t)64 * 2048 * 64 * 2);
  unsigned short* Kh  = (unsigned short*)alloc((size_t)64 * 2048 * 64 * 2);
  unsigned short* Vh  = (unsigned short*)alloc((size_t)64 * 2048 * 64 * 2);
  unsigned short* Vt  = (unsigned short*)alloc((size_t)64 * 2048 * 64 * 2);
  unsigned short* ctx = (unsigned short*)alloc((size_t)8192 * 1024 * 2);

  k_cvt<<<dim3(2048), dim3(256), 0, stream>>>(x, xb, (8192 * 1024) / 4);
  k_tpose_cvt<<<dim3(48, 16), dim3(256), 0, stream>>>(W_attn, Wta, 1024, 3072);
  k_tpose_cvt<<<dim3(16, 16), dim3(256), 0, stream>>>(W_proj, Wtp, 1024, 1024);
  k_gemm_qkv<<<dim3(768), dim3(512), 0, stream>>>(xb, Wta, b_attn, Qh, Kh, Vh);
  k_tpose_v<<<dim3(32, 64), dim3(256), 0, stream>>>(Vh, Vt);
  k_attn<<<dim3(1024), dim3(256), 0, stream>>>(Qh, Kh, Vt, ctx);
  k_gemm_proj<<<dim3(512), dim3(256), 0, stream>>>(ctx, Wtp, b_proj, out, 1024);
}